// Round 1
// baseline (493.047 us; speedup 1.0000x reference)
//
#include <hip/hip_runtime.h>
#include <hip/hip_bf16.h>

// Problem constants
// B=128, CIN=3, H=W=32, C1=64, C2=256, NUM_CLASSES=1000
// K_CONV=48 (top-48 of 256 gate scores), K_FC=12451 >= 48*256=12288
// => FC reduces exactly to the 48 selected channels' pooled features.

#define NB 128
#define NC1 64
#define NC2 256
#define NSEL 48
#define NCLS 1000

// ---------------- K1: conv1 (3->64, 3x3, pad1) + ReLU + per-(c,b) |.| sums --------
__global__ __launch_bounds__(256) void k1_conv1(
    const float* __restrict__ x0, const float* __restrict__ w1,
    const float* __restrict__ b1, float* __restrict__ x1,
    float* __restrict__ part) {
  const int b = blockIdx.x;   // 0..127
  const int c = blockIdx.y;   // 0..63
  const int t = threadIdx.x;  // 0..255
  __shared__ float xs[3 * 1056];  // 3 planes, rows padded to 33
  __shared__ float wsm[28];
  __shared__ float red[4];

  // stage 3 input planes (padded rows)
  const float4* x0v = reinterpret_cast<const float4*>(x0 + (size_t)b * 3 * 1024);
  {
    const int p = t * 4;
    const int h = p >> 5, w0p = p & 31;
#pragma unroll
    for (int ic = 0; ic < 3; ++ic) {
      float4 v = x0v[ic * 256 + t];
      float* dst = xs + ic * 1056 + h * 33 + w0p;
      dst[0] = v.x; dst[1] = v.y; dst[2] = v.z; dst[3] = v.w;
    }
  }
  if (t < 27) wsm[t] = w1[c * 27 + t];
  if (t == 27) wsm[27] = b1[c];
  __syncthreads();

  const int h = t >> 3;          // 0..31
  const int w0 = (t & 7) * 4;    // 0,4,...,28
  float acc[4];
  const float bias = wsm[27];
#pragma unroll
  for (int j = 0; j < 4; ++j) acc[j] = bias;

#pragma unroll
  for (int ic = 0; ic < 3; ++ic) {
    const float* pl = xs + ic * 1056;
    const float* wp = wsm + ic * 9;
#pragma unroll
    for (int kh = 0; kh < 3; ++kh) {
      const int hy = h + kh - 1;
      if (hy >= 0 && hy < 32) {
        float seg[6];
#pragma unroll
        for (int d = 0; d < 6; ++d) {
          const int wx = w0 - 1 + d;
          seg[d] = (wx >= 0 && wx < 32) ? pl[hy * 33 + wx] : 0.f;
        }
        const float wa = wp[kh * 3 + 0], wb = wp[kh * 3 + 1], wc = wp[kh * 3 + 2];
#pragma unroll
        for (int j = 0; j < 4; ++j)
          acc[j] += seg[j] * wa + seg[j + 1] * wb + seg[j + 2] * wc;
      }
    }
  }
  float s = 0.f;
  float4 outv;
#pragma unroll
  for (int j = 0; j < 4; ++j) {
    float v = acc[j] > 0.f ? acc[j] : 0.f;
    (&outv.x)[j] = v;
    s += v;  // |relu(x)| == relu(x)
  }
  reinterpret_cast<float4*>(x1 + ((size_t)(b * 64 + c)) * 1024)[t] = outv;

  for (int off = 32; off > 0; off >>= 1) s += __shfl_down(s, off, 64);
  if ((t & 63) == 0) red[t >> 6] = s;
  __syncthreads();
  if (t == 0) part[c * 128 + b] = red[0] + red[1] + red[2] + red[3];
}

// ---------------- K2: sig -> gate logits -> top-48 selection ----------------------
__global__ __launch_bounds__(256) void k2_select(
    const float* __restrict__ part, const float* __restrict__ gate_w,
    int* __restrict__ sel) {
  const int t = threadIdx.x;
  __shared__ float red[256];
  __shared__ float sig[64];
  __shared__ float sc[256];
  __shared__ int flag[256];
  {
    const int c = t >> 2, q = t & 3;
    float s = 0.f;
    for (int i = 0; i < 32; ++i) s += part[c * 128 + q * 32 + i];
    red[t] = s;
  }
  __syncthreads();
  if (t < 64)
    sig[t] = (red[4 * t] + red[4 * t + 1] + red[4 * t + 2] + red[4 * t + 3]) *
             (1.0f / 131072.0f);
  __syncthreads();
  {
    float lg = 0.f;
    for (int i = 0; i < 64; ++i) lg += gate_w[t * 64 + i] * sig[i];
    sc[t] = lg;  // softplus is monotone -> rank by logits
  }
  __syncthreads();
  {
    const float v = sc[t];
    int r = 0;
    for (int j = 0; j < 256; ++j) {
      const float vj = sc[j];
      r += (vj > v) || (vj == v && j < t);
    }
    flag[t] = (r < NSEL) ? 1 : 0;
  }
  __syncthreads();
  if (flag[t]) {
    int pos = 0;
    for (int j = 0; j < t; ++j) pos += flag[j];
    sel[pos] = t;
  }
}

// ---------------- K3: conv2 (64->48 sel, 3x3, pad1) + ReLU + 2x2 maxpool ----------
__global__ __launch_bounds__(256) void k3_conv2(
    const float* __restrict__ x1, const float* __restrict__ w2,
    const float* __restrict__ b2, const int* __restrict__ sel,
    float* __restrict__ pooled) {
  const int b = blockIdx.x;  // 0..127
  const int g = blockIdx.y;  // 0..5  (8 output channels each)
  const int t = threadIdx.x;
  __shared__ float plane[1024];

  int so[8];
#pragma unroll
  for (int o = 0; o < 8; ++o)
    so[o] = __builtin_amdgcn_readfirstlane(sel[g * 8 + o]);

  float acc[8][4];
#pragma unroll
  for (int o = 0; o < 8; ++o) {
    const float bv = b2[so[o]];
#pragma unroll
    for (int j = 0; j < 4; ++j) acc[o][j] = bv;
  }

  const int py = t >> 4, px = t & 15;
  const float4* x1v = reinterpret_cast<const float4*>(x1 + ((size_t)b * 64) * 1024);

  for (int ic = 0; ic < 64; ++ic) {
    __syncthreads();
    reinterpret_cast<float4*>(plane)[t] = x1v[ic * 256 + t];
    __syncthreads();

    float win[4][4];
#pragma unroll
    for (int rr = 0; rr < 4; ++rr) {
      const int row = 2 * py - 1 + rr;
#pragma unroll
      for (int cc = 0; cc < 4; ++cc) {
        const int col = 2 * px - 1 + cc;
        win[rr][cc] = (row >= 0 && row < 32 && col >= 0 && col < 32)
                          ? plane[row * 32 + col] : 0.f;
      }
    }
#pragma unroll
    for (int o = 0; o < 8; ++o) {
      const float* wp = w2 + (size_t)so[o] * 576 + ic * 9;  // uniform -> s_load
      float w9[9];
#pragma unroll
      for (int k = 0; k < 9; ++k) w9[k] = wp[k];
#pragma unroll
      for (int pr = 0; pr < 2; ++pr)
#pragma unroll
        for (int pc = 0; pc < 2; ++pc) {
          float a = acc[o][pr * 2 + pc];
#pragma unroll
          for (int kh = 0; kh < 3; ++kh)
#pragma unroll
            for (int kw = 0; kw < 3; ++kw)
              a += win[pr + kh][pc + kw] * w9[kh * 3 + kw];
          acc[o][pr * 2 + pc] = a;
        }
    }
  }
#pragma unroll
  for (int o = 0; o < 8; ++o) {
    float m = fmaxf(fmaxf(acc[o][0], acc[o][1]), fmaxf(acc[o][2], acc[o][3]));
    m = fmaxf(m, 0.f);  // relu then maxpool == max(max4, 0)
    pooled[((size_t)b * 48 + g * 8 + o) * 256 + t] = m;
  }
}

// ---------------- K4: FC partials. BM=128, BN=32, K split 8 ways ------------------
__global__ __launch_bounds__(256) void k4_fc(
    const float* __restrict__ pooled, const float* __restrict__ fc_w,
    const int* __restrict__ sel, float* __restrict__ partial) {
  const int nb = blockIdx.x;  // 0..31
  const int ks = blockIdx.y;  // 0..7
  const int t = threadIdx.x;
  const int wv = __builtin_amdgcn_readfirstlane(t >> 6);  // wave id 0..3
  const int lane = t & 63;
  __shared__ float pk[128 * 65];

  const int n0 = nb * 32 + wv * 8;
  const bool nvalid = (n0 < NCLS);
  const int n0e = nvalid ? n0 : 0;

  float acc[2][8];
#pragma unroll
  for (int e = 0; e < 2; ++e)
#pragma unroll
    for (int i = 0; i < 8; ++i) acc[e][i] = 0.f;

  const int b0 = lane * 2;
  const int kbeg = ks * 1536;
  for (int kk = kbeg; kk < kbeg + 1536; kk += 64) {
    __syncthreads();
#pragma unroll
    for (int r = 0; r < 8; ++r) {
      const int s = r * 256 + t;       // 0..2047 float4 slots
      const int bp = s >> 4, kq = s & 15;
      float4 v = reinterpret_cast<const float4*>(pooled)[bp * 3072 + (kk >> 2) + kq];
      float* dst = pk + bp * 65 + kq * 4;
      dst[0] = v.x; dst[1] = v.y; dst[2] = v.z; dst[3] = v.w;
    }
    __syncthreads();

    const int c = __builtin_amdgcn_readfirstlane(sel[kk >> 8]);
    const float* wbase = fc_w + (size_t)c * 256 + (kk & 255);
#pragma unroll 8
    for (int k = 0; k < 64; ++k) {
      const float a0 = pk[b0 * 65 + k];
      const float a1 = pk[b0 * 65 + 65 + k];
#pragma unroll
      for (int i = 0; i < 8; ++i) {
        const float wvv = wbase[(size_t)(n0e + i) * 65536 + k];  // uniform -> s_load
        acc[0][i] += a0 * wvv;
        acc[1][i] += a1 * wvv;
      }
    }
  }
  if (nvalid) {
#pragma unroll
    for (int i = 0; i < 8; ++i) {
      float2 v = make_float2(acc[0][i], acc[1][i]);
      reinterpret_cast<float2*>(partial + ((size_t)ks * NCLS + n0 + i) * 128)[lane] = v;
    }
  }
}

// ---------------- K5: reduce K-split partials + bias ------------------------------
__global__ __launch_bounds__(256) void k5_reduce(
    const float* __restrict__ partial, const float* __restrict__ fc_b,
    float* __restrict__ out) {
  const int id = blockIdx.x * 256 + threadIdx.x;  // 0..127999
  const int n = id >> 7;
  const int b = id & 127;
  float s = fc_b[n];
#pragma unroll
  for (int ks = 0; ks < 8; ++ks) s += partial[(size_t)ks * 128000 + id];
  out[(size_t)b * NCLS + n] = s;
}

extern "C" void kernel_launch(void* const* d_in, const int* in_sizes, int n_in,
                              void* d_out, int out_size, void* d_ws, size_t ws_size,
                              hipStream_t stream) {
  (void)in_sizes; (void)n_in; (void)out_size; (void)ws_size;
  const float* x0     = (const float*)d_in[0];
  const float* w1     = (const float*)d_in[1];
  const float* b1     = (const float*)d_in[2];
  const float* gate_w = (const float*)d_in[3];
  const float* w2     = (const float*)d_in[4];
  const float* b2     = (const float*)d_in[5];
  const float* fc_w   = (const float*)d_in[6];
  const float* fc_b   = (const float*)d_in[7];
  float* out = (float*)d_out;

  char* ws = (char*)d_ws;
  float* x1     = (float*)(ws);                         // 128*64*1024 f  = 33.55 MB
  float* pooled = (float*)(ws + 33554432);              // 128*48*256 f   = 6.29 MB
  float* part   = (float*)(ws + 39845888);              // 64*128 f
  int*   sel    = (int*)  (ws + 39878656);              // 48 ints
  float* fcpart = (float*)(ws + 39878912);              // 8*1000*128 f   = 4.10 MB

  hipLaunchKernelGGL(k1_conv1, dim3(128, 64), dim3(256), 0, stream, x0, w1, b1, x1, part);
  hipLaunchKernelGGL(k2_select, dim3(1), dim3(256), 0, stream, part, gate_w, sel);
  hipLaunchKernelGGL(k3_conv2, dim3(128, 6), dim3(256), 0, stream, x1, w2, b2, sel, pooled);
  hipLaunchKernelGGL(k4_fc, dim3(32, 8), dim3(256), 0, stream, pooled, fc_w, sel, fcpart);
  hipLaunchKernelGGL(k5_reduce, dim3(500), dim3(256), 0, stream, fcpart, fc_b, out);
}

// Round 2
// 166.274 us; speedup vs baseline: 2.9653x; 2.9653x over previous
//
#include <hip/hip_runtime.h>
#include <hip/hip_bf16.h>

// B=128, CIN=3, H=W=32, C1=64, C2=256, NUM_CLASSES=1000
// K_CONV=48, K_FC=12451 >= 48*256 => FC reduces exactly to the 48 selected
// channels' pooled features (non-selected channels are exactly zero).

#define NSEL 48
#define NCLS 1000

__device__ __forceinline__ unsigned short f2bf(float x) {
  unsigned u = __builtin_bit_cast(unsigned, x);
  u += 0x7fffu + ((u >> 16) & 1u);   // RNE (inputs finite)
  return (unsigned short)(u >> 16);
}

// ---------------- K1: conv1 (3->64, 3x3, pad1) + ReLU + per-(c,b) |.| sums --------
__global__ __launch_bounds__(256) void k1_conv1(
    const float* __restrict__ x0, const float* __restrict__ w1,
    const float* __restrict__ b1, float* __restrict__ x1,
    float* __restrict__ part) {
  const int b = blockIdx.x;   // 0..127
  const int c = blockIdx.y;   // 0..63
  const int t = threadIdx.x;  // 0..255
  __shared__ float xs[3 * 1056];  // 3 planes, rows padded to 33
  __shared__ float wsm[28];
  __shared__ float red[4];

  const float4* x0v = reinterpret_cast<const float4*>(x0 + (size_t)b * 3 * 1024);
  {
    const int p = t * 4;
    const int h = p >> 5, w0p = p & 31;
#pragma unroll
    for (int ic = 0; ic < 3; ++ic) {
      float4 v = x0v[ic * 256 + t];
      float* dst = xs + ic * 1056 + h * 33 + w0p;
      dst[0] = v.x; dst[1] = v.y; dst[2] = v.z; dst[3] = v.w;
    }
  }
  if (t < 27) wsm[t] = w1[c * 27 + t];
  if (t == 27) wsm[27] = b1[c];
  __syncthreads();

  const int h = t >> 3;
  const int w0 = (t & 7) * 4;
  float acc[4];
  const float bias = wsm[27];
#pragma unroll
  for (int j = 0; j < 4; ++j) acc[j] = bias;

#pragma unroll
  for (int ic = 0; ic < 3; ++ic) {
    const float* pl = xs + ic * 1056;
    const float* wp = wsm + ic * 9;
#pragma unroll
    for (int kh = 0; kh < 3; ++kh) {
      const int hy = h + kh - 1;
      if (hy >= 0 && hy < 32) {
        float seg[6];
#pragma unroll
        for (int d = 0; d < 6; ++d) {
          const int wx = w0 - 1 + d;
          seg[d] = (wx >= 0 && wx < 32) ? pl[hy * 33 + wx] : 0.f;
        }
        const float wa = wp[kh * 3 + 0], wb = wp[kh * 3 + 1], wc = wp[kh * 3 + 2];
#pragma unroll
        for (int j = 0; j < 4; ++j)
          acc[j] += seg[j] * wa + seg[j + 1] * wb + seg[j + 2] * wc;
      }
    }
  }
  float s = 0.f;
  float4 outv;
#pragma unroll
  for (int j = 0; j < 4; ++j) {
    float v = acc[j] > 0.f ? acc[j] : 0.f;
    (&outv.x)[j] = v;
    s += v;
  }
  reinterpret_cast<float4*>(x1 + ((size_t)(b * 64 + c)) * 1024)[t] = outv;

  for (int off = 32; off > 0; off >>= 1) s += __shfl_down(s, off, 64);
  if ((t & 63) == 0) red[t >> 6] = s;
  __syncthreads();
  if (t == 0) part[c * 128 + b] = red[0] + red[1] + red[2] + red[3];
}

// ---------------- K2: sig -> gate logits -> top-48 selection ----------------------
__global__ __launch_bounds__(256) void k2_select(
    const float* __restrict__ part, const float* __restrict__ gate_w,
    int* __restrict__ sel) {
  const int t = threadIdx.x;
  __shared__ float red[256];
  __shared__ float sig[64];
  __shared__ float sc[256];
  __shared__ int flag[256];
  {
    const int c = t >> 2, q = t & 3;
    float s = 0.f;
    for (int i = 0; i < 32; ++i) s += part[c * 128 + q * 32 + i];
    red[t] = s;
  }
  __syncthreads();
  if (t < 64)
    sig[t] = (red[4 * t] + red[4 * t + 1] + red[4 * t + 2] + red[4 * t + 3]) *
             (1.0f / 131072.0f);
  __syncthreads();
  {
    float lg = 0.f;
    for (int i = 0; i < 64; ++i) lg += gate_w[t * 64 + i] * sig[i];
    sc[t] = lg;  // softplus monotone -> rank by logits
  }
  __syncthreads();
  {
    const float v = sc[t];
    int r = 0;
    for (int j = 0; j < 256; ++j) {
      const float vj = sc[j];
      r += (vj > v) || (vj == v && j < t);
    }
    flag[t] = (r < NSEL) ? 1 : 0;
  }
  __syncthreads();
  if (flag[t]) {
    int pos = 0;
    for (int j = 0; j < t; ++j) pos += flag[j];
    sel[pos] = t;
  }
}

// ---------------- K3: conv2 (64->48 sel) + ReLU + 2x2 maxpool -> bf16 frag layout -
// pooledt layout: [kb = slot_k/8][b 128][8] bf16, slot_k = j*256 + p, j = sel slot.
__global__ __launch_bounds__(256) void k3_conv2(
    const float* __restrict__ x1, const float* __restrict__ w2,
    const float* __restrict__ b2, const int* __restrict__ sel,
    unsigned short* __restrict__ pooledt) {
  const int b = blockIdx.x;  // 0..127
  const int g = blockIdx.y;  // 0..5
  const int t = threadIdx.x;
  __shared__ float plane[1024];

  int so[8];
#pragma unroll
  for (int o = 0; o < 8; ++o)
    so[o] = __builtin_amdgcn_readfirstlane(sel[g * 8 + o]);

  float acc[8][4];
#pragma unroll
  for (int o = 0; o < 8; ++o) {
    const float bv = b2[so[o]];
#pragma unroll
    for (int j = 0; j < 4; ++j) acc[o][j] = bv;
  }

  const int py = t >> 4, px = t & 15;
  const float4* x1v = reinterpret_cast<const float4*>(x1 + ((size_t)b * 64) * 1024);

  for (int ic = 0; ic < 64; ++ic) {
    __syncthreads();
    reinterpret_cast<float4*>(plane)[t] = x1v[ic * 256 + t];
    __syncthreads();

    float win[4][4];
#pragma unroll
    for (int rr = 0; rr < 4; ++rr) {
      const int row = 2 * py - 1 + rr;
#pragma unroll
      for (int cc = 0; cc < 4; ++cc) {
        const int col = 2 * px - 1 + cc;
        win[rr][cc] = (row >= 0 && row < 32 && col >= 0 && col < 32)
                          ? plane[row * 32 + col] : 0.f;
      }
    }
#pragma unroll
    for (int o = 0; o < 8; ++o) {
      const float* wp = w2 + (size_t)so[o] * 576 + ic * 9;  // uniform -> s_load
      float w9[9];
#pragma unroll
      for (int k = 0; k < 9; ++k) w9[k] = wp[k];
#pragma unroll
      for (int pr = 0; pr < 2; ++pr)
#pragma unroll
        for (int pc = 0; pc < 2; ++pc) {
          float a = acc[o][pr * 2 + pc];
#pragma unroll
          for (int kh = 0; kh < 3; ++kh)
#pragma unroll
            for (int kw = 0; kw < 3; ++kw)
              a += win[pr + kh][pc + kw] * w9[kh * 3 + kw];
          acc[o][pr * 2 + pc] = a;
        }
    }
  }
#pragma unroll
  for (int o = 0; o < 8; ++o) {
    float m = fmaxf(fmaxf(acc[o][0], acc[o][1]), fmaxf(acc[o][2], acc[o][3]));
    m = fmaxf(m, 0.f);
    const int j = g * 8 + o;
    const int kb = j * 32 + (t >> 3);
    pooledt[((size_t)kb * 128 + b) * 8 + (t & 7)] = f2bf(m);
  }
}

// ---------------- K4: bf16 MFMA GEMM partials. BM=128, BN=32, K split 8 -----------
__global__ __launch_bounds__(256) void k4_fc(
    const unsigned short* __restrict__ pooledt, const float* __restrict__ fc_w,
    const int* __restrict__ sel, float* __restrict__ fcpart) {
  const int ntile = blockIdx.x;  // 0..31  (BN=32)
  const int ks = blockIdx.y;     // 0..7   (K chunk = 1536 = 6 channels)
  const int t = threadIdx.x;
  const int w = t >> 6, l = t & 63;

  __shared__ short Ab[2][8192];  // [ko 8][m 128][8] bf16
  __shared__ short Bb[2][2048];  // [ko 8][n 32][8] bf16

  using sh8 = __attribute__((ext_vector_type(8))) short;
  using f4  = __attribute__((ext_vector_type(4))) float;

  f4 acc[2][2];
  const f4 fzero = {0.f, 0.f, 0.f, 0.f};
#pragma unroll
  for (int i = 0; i < 2; ++i)
#pragma unroll
    for (int j = 0; j < 2; ++j) acc[i][j] = fzero;

  // channels this block touches (wave-uniform scalar loads)
  int ch[6];
#pragma unroll
  for (int i = 0; i < 6; ++i)
    ch[i] = __builtin_amdgcn_readfirstlane(sel[ks * 6 + i]);

  const int n0 = ntile * 32;
  const int nl = t & 31;
  int ng = n0 + nl; if (ng > 999) ng = 999;   // clamp tail rows (cols ignored in k5)
  const int kh = t >> 5;  // 0..7 : k-oct within tile
  const float* wrow = fc_w + (size_t)ng * 65536 + kh * 8;

  const int4* pt = reinterpret_cast<const int4*>(pooledt);
  const int kb0 = ks * 192;  // (ks*1536)/8 : 16B-block base in pooledt

  int4 av[4];
  float4 bv0, bv1;

  // ---- stage tile 0 ----
  {
#pragma unroll
    for (int it = 0; it < 4; ++it) {
      const int s = it * 256 + t, ko = s >> 7, m = s & 127;
      av[it] = pt[(kb0 + ko) * 128 + m];
    }
    const float* bp = wrow + ch[0] * 256;  // tile 0: within-channel offset 0
    bv0 = *reinterpret_cast<const float4*>(bp);
    bv1 = *reinterpret_cast<const float4*>(bp + 4);
#pragma unroll
    for (int it = 0; it < 4; ++it)
      *reinterpret_cast<int4*>(&Ab[0][(it * 256 + t) * 8]) = av[it];
    int4 bw;
    bw.x = f2bf(bv0.x) | ((unsigned)f2bf(bv0.y) << 16);
    bw.y = f2bf(bv0.z) | ((unsigned)f2bf(bv0.w) << 16);
    bw.z = f2bf(bv1.x) | ((unsigned)f2bf(bv1.y) << 16);
    bw.w = f2bf(bv1.z) | ((unsigned)f2bf(bv1.w) << 16);
    *reinterpret_cast<int4*>(&Bb[0][(kh * 32 + nl) * 8]) = bw;
  }
  __syncthreads();

  for (int tt = 0; tt < 24; ++tt) {
    const int cur = tt & 1, nxt = cur ^ 1;
    if (tt < 23) {
      const int tn = tt + 1;
#pragma unroll
      for (int it = 0; it < 4; ++it) {
        const int s = it * 256 + t, ko = s >> 7, m = s & 127;
        av[it] = pt[(kb0 + tn * 8 + ko) * 128 + m];
      }
      const float* bp = wrow + ch[tn >> 2] * 256 + (tn & 3) * 64;
      bv0 = *reinterpret_cast<const float4*>(bp);
      bv1 = *reinterpret_cast<const float4*>(bp + 4);
    }

    // compute current tile: 2 k-substeps of 32
#pragma unroll
    for (int s2 = 0; s2 < 2; ++s2) {
      const int kg = s2 * 4 + (l >> 4);
      const int m0 = w * 32 + (l & 15);
      sh8 a0 = *reinterpret_cast<const sh8*>(&Ab[cur][(kg * 128 + m0) * 8]);
      sh8 a1 = *reinterpret_cast<const sh8*>(&Ab[cur][(kg * 128 + m0 + 16) * 8]);
      sh8 b0 = *reinterpret_cast<const sh8*>(&Bb[cur][(kg * 32 + (l & 15)) * 8]);
      sh8 b1 = *reinterpret_cast<const sh8*>(&Bb[cur][(kg * 32 + 16 + (l & 15)) * 8]);
      acc[0][0] = __builtin_amdgcn_mfma_f32_16x16x32_bf16(a0, b0, acc[0][0], 0, 0, 0);
      acc[0][1] = __builtin_amdgcn_mfma_f32_16x16x32_bf16(a0, b1, acc[0][1], 0, 0, 0);
      acc[1][0] = __builtin_amdgcn_mfma_f32_16x16x32_bf16(a1, b0, acc[1][0], 0, 0, 0);
      acc[1][1] = __builtin_amdgcn_mfma_f32_16x16x32_bf16(a1, b1, acc[1][1], 0, 0, 0);
    }

    if (tt < 23) {
#pragma unroll
      for (int it = 0; it < 4; ++it)
        *reinterpret_cast<int4*>(&Ab[nxt][(it * 256 + t) * 8]) = av[it];
      int4 bw;
      bw.x = f2bf(bv0.x) | ((unsigned)f2bf(bv0.y) << 16);
      bw.y = f2bf(bv0.z) | ((unsigned)f2bf(bv0.w) << 16);
      bw.z = f2bf(bv1.x) | ((unsigned)f2bf(bv1.y) << 16);
      bw.w = f2bf(bv1.z) | ((unsigned)f2bf(bv1.w) << 16);
      *reinterpret_cast<int4*>(&Bb[nxt][(kh * 32 + nl) * 8]) = bw;
    }
    __syncthreads();
  }

  // epilogue: C frag mapping col=lane&15, row=(lane>>4)*4+reg
  const int r0 = (l >> 4) * 4;
#pragma unroll
  for (int fm = 0; fm < 2; ++fm)
#pragma unroll
    for (int fn = 0; fn < 2; ++fn)
#pragma unroll
      for (int r = 0; r < 4; ++r) {
        const int m = w * 32 + fm * 16 + r0 + r;
        const int nc = n0 + fn * 16 + (l & 15);
        fcpart[(((size_t)ks * 128 + m) << 10) + nc] = acc[fm][fn][r];
      }
}

// ---------------- K5: reduce K-split partials + bias ------------------------------
__global__ __launch_bounds__(256) void k5_reduce(
    const float* __restrict__ fcpart, const float* __restrict__ fc_b,
    float* __restrict__ out) {
  const int id = blockIdx.x * 256 + threadIdx.x;  // 0..127999
  const int b = id / 1000;
  const int n = id - b * 1000;
  float s = fc_b[n];
#pragma unroll
  for (int ks = 0; ks < 8; ++ks)
    s += fcpart[(((size_t)ks * 128 + b) << 10) + n];
  out[id] = s;
}

extern "C" void kernel_launch(void* const* d_in, const int* in_sizes, int n_in,
                              void* d_out, int out_size, void* d_ws, size_t ws_size,
                              hipStream_t stream) {
  (void)in_sizes; (void)n_in; (void)out_size; (void)ws_size;
  const float* x0     = (const float*)d_in[0];
  const float* w1     = (const float*)d_in[1];
  const float* b1     = (const float*)d_in[2];
  const float* gate_w = (const float*)d_in[3];
  const float* w2     = (const float*)d_in[4];
  const float* b2     = (const float*)d_in[5];
  const float* fc_w   = (const float*)d_in[6];
  const float* fc_b   = (const float*)d_in[7];
  float* out = (float*)d_out;

  char* ws = (char*)d_ws;
  float*          x1      = (float*)(ws);                    // 33,554,432 B
  unsigned short* pooledt = (unsigned short*)(ws + 33554432); // 3,145,728 B
  float*          part    = (float*)(ws + 36700160);          //    32,768 B
  int*            sel     = (int*)  (ws + 36732928);          //       256 B
  float*          fcpart  = (float*)(ws + 36733184);          // 4,194,304 B (ends ~40.9MB)

  hipLaunchKernelGGL(k1_conv1, dim3(128, 64), dim3(256), 0, stream, x0, w1, b1, x1, part);
  hipLaunchKernelGGL(k2_select, dim3(1), dim3(256), 0, stream, part, gate_w, sel);
  hipLaunchKernelGGL(k3_conv2, dim3(128, 6), dim3(256), 0, stream, x1, w2, b2, sel, pooledt);
  hipLaunchKernelGGL(k4_fc, dim3(32, 8), dim3(256), 0, stream, pooledt, fc_w, sel, fcpart);
  hipLaunchKernelGGL(k5_reduce, dim3(500), dim3(256), 0, stream, fcpart, fc_b, out);
}

// Round 3
// 112.405 us; speedup vs baseline: 4.3863x; 1.4792x over previous
//
#include <hip/hip_runtime.h>
#include <hip/hip_bf16.h>

// B=128, CIN=3, H=W=32, C1=64, C2=256, NUM_CLASSES=1000
// K_CONV=48, K_FC=12451 >= 48*256 => FC reduces exactly to the 48 selected
// channels' pooled features (non-selected channels are exactly zero).

#define NSEL 48
#define NCLS 1000

__device__ __forceinline__ unsigned short f2bf(float x) {
  unsigned u = __builtin_bit_cast(unsigned, x);
  u += 0x7fffu + ((u >> 16) & 1u);  // RNE (finite inputs)
  return (unsigned short)(u >> 16);
}

__device__ __forceinline__ void gl_lds16(const void* g, void* l) {
  __builtin_amdgcn_global_load_lds(
      (const __attribute__((address_space(1))) void*)g,
      (__attribute__((address_space(3))) void*)l, 16, 0, 0);
}

using sh8 = __attribute__((ext_vector_type(8))) short;
using f4  = __attribute__((ext_vector_type(4))) float;

// ---------------- K1: conv1 + ReLU -> x1 bf16 [b][pix][64ic]; |.| partial sums ----
// grid (128 b, 4 quarter), 256 thr; quarter = 8 output rows.
__global__ __launch_bounds__(256) void k1_conv1(
    const float* __restrict__ x0, const float* __restrict__ w1,
    const float* __restrict__ b1, unsigned short* __restrict__ x1,
    float* __restrict__ part2) {
  const int b = blockIdx.x, quarter = blockIdx.y;
  const int t = threadIdx.x;
  const int wv = t >> 6;
  __shared__ float xs[3 * 320];   // 3 ic x 10 rows x 32 cols
  __shared__ float wred[64 * 4];
  const int r0 = quarter * 8;

  for (int q = 0; q < 15; ++q) {  // 3840 floats
    const int id = q * 256 + t;
    const int ic = id / 320;
    const int rem = id - ic * 320;
    const int row = rem >> 5, col = rem & 31;
    const int gr = r0 - 1 + row;
    xs[id] = ((unsigned)gr < 32u)
                 ? x0[((size_t)b * 3 + ic) * 1024 + gr * 32 + col] : 0.f;
  }
  __syncthreads();

  const int lr = t >> 5, pc = t & 31;  // local out row 0..7, col 0..31
  float win[3][3][3];
#pragma unroll
  for (int ic = 0; ic < 3; ++ic)
#pragma unroll
    for (int kr = 0; kr < 3; ++kr)
#pragma unroll
      for (int kc = 0; kc < 3; ++kc) {
        const int cc = pc - 1 + kc;
        win[ic][kr][kc] = ((unsigned)cc < 32u) ? xs[ic * 320 + (lr + kr) * 32 + cc] : 0.f;
      }

  unsigned pk[32];
#pragma unroll
  for (int oc = 0; oc < 64; ++oc) {
    float a = b1[oc];
#pragma unroll
    for (int ic = 0; ic < 3; ++ic)
#pragma unroll
      for (int kr = 0; kr < 3; ++kr)
#pragma unroll
        for (int kc = 0; kc < 3; ++kc)
          a += w1[oc * 27 + ic * 9 + kr * 3 + kc] * win[ic][kr][kc];
    const float v = a > 0.f ? a : 0.f;
    const unsigned bf = f2bf(v);
    if (oc & 1) pk[oc >> 1] |= bf << 16; else pk[oc >> 1] = bf;
    float rs = v;
    for (int off = 32; off > 0; off >>= 1) rs += __shfl_down(rs, off, 64);
    if ((t & 63) == 0) wred[oc * 4 + wv] = rs;
  }

  {  // write one 128-B ic-row per thread
    int4* dst = reinterpret_cast<int4*>(x1) +
                ((size_t)b * 1024 + (r0 + lr) * 32 + pc) * 8;
    const int4* src = reinterpret_cast<const int4*>(pk);
#pragma unroll
    for (int j2 = 0; j2 < 8; ++j2) dst[j2] = src[j2];
  }
  __syncthreads();
  if (t < 64) {
    const float s = wred[t * 4] + wred[t * 4 + 1] + wred[t * 4 + 2] + wred[t * 4 + 3];
    part2[((size_t)quarter * 64 + t) * 128 + b] = s;
  }
}

// ---------------- K2: sig -> gate logits -> top-48 selection ----------------------
__global__ __launch_bounds__(256) void k2_select(
    const float* __restrict__ part2, const float* __restrict__ gate_w,
    int* __restrict__ sel) {
  const int t = threadIdx.x;
  __shared__ float red[256];
  __shared__ float sig[64];
  __shared__ float sc[256];
  __shared__ int flag[256];
  {
    const int c = t >> 2, q = t & 3;
    float s = 0.f;
    for (int h = 0; h < 4; ++h)
      for (int i = 0; i < 32; ++i)
        s += part2[((size_t)h * 64 + c) * 128 + q * 32 + i];
    red[t] = s;
  }
  __syncthreads();
  if (t < 64)
    sig[t] = (red[4 * t] + red[4 * t + 1] + red[4 * t + 2] + red[4 * t + 3]) *
             (1.0f / 131072.0f);
  __syncthreads();
  {
    float lg = 0.f;
    for (int i = 0; i < 64; ++i) lg += gate_w[t * 64 + i] * sig[i];
    sc[t] = lg;  // softplus monotone -> rank by logits
  }
  __syncthreads();
  {
    const float v = sc[t];
    int r = 0;
    for (int j = 0; j < 256; ++j) {
      const float vj = sc[j];
      r += (vj > v) || (vj == v && j < t);
    }
    flag[t] = (r < NSEL) ? 1 : 0;
  }
  __syncthreads();
  if (flag[t]) {
    int pos = 0;
    for (int j = 0; j < t; ++j) pos += flag[j];
    sel[pos] = t;
  }
}

// ---------------- K2b: gather/transpose conv2 weights -> w2t[9][48][64] bf16 ------
__global__ __launch_bounds__(256) void k2b_wprep(
    const float* __restrict__ w2, const float* __restrict__ b2,
    const int* __restrict__ sel, unsigned short* __restrict__ w2t,
    float* __restrict__ b2s) {
  const int j = blockIdx.x;  // 0..47 selection slot
  const int t = threadIdx.x;
  const int c = sel[j];
  if (t == 0) b2s[j] = b2[c];
  for (int id = t; id < 576; id += 256) {
    const float v = w2[(size_t)c * 576 + id];
    const int ic = id / 9;
    const int s = id - ic * 9;
    w2t[((size_t)s * 48 + j) * 64 + ic] = f2bf(v);
  }
}

// ---------------- K3: conv2 via 9-shift bf16 MFMA + bias + ReLU + maxpool ---------
// grid (128 b, 4 quarter), 256 thr (4 waves). M=256 pix (8 rows), N=48, K=64 x 9.
__global__ __launch_bounds__(256) void k3_conv2(
    const unsigned short* __restrict__ x1, const unsigned short* __restrict__ w2t,
    const float* __restrict__ b2s, unsigned short* __restrict__ pooledt) {
  const int b = blockIdx.x, quarter = blockIdx.y;
  const int t = threadIdx.x;
  const int w = t >> 6, l = t & 63;
  const int q4 = l >> 4, ln15 = l & 15;
  __shared__ short xt[20480];  // 10 rows x 32 cols x 64 ic bf16, 16B-slot swizzled

  const int r0 = quarter * 8;

  // stage halo'd rows: LDS linear, swizzle folded into per-lane global source
  for (int q = 0; q < 10; ++q) {
    const int S = (w * 10 + q) * 64 + l;  // 16B-slot id 0..2559
    const int pix = S >> 3, slot = S & 7;
    const int row = pix >> 5, col = pix & 31;
    int gr = r0 - 1 + row;
    gr = gr < 0 ? 0 : (gr > 31 ? 31 : gr);  // clamped rows masked at use
    const unsigned short* gsrc =
        x1 + ((size_t)(b * 1024 + gr * 32 + col) * 64) + (slot ^ (pix & 7)) * 8;
    gl_lds16((const void*)gsrc, (void*)&xt[(w * 10 + q) * 512]);
  }
  __syncthreads();

  f4 acc[4][3];
  const f4 fz = {0.f, 0.f, 0.f, 0.f};
#pragma unroll
  for (int i = 0; i < 4; ++i)
#pragma unroll
    for (int nt = 0; nt < 3; ++nt) acc[i][nt] = fz;

  const int w4 = w * 4;
  const sh8 zz = {0, 0, 0, 0, 0, 0, 0, 0};

#pragma unroll
  for (int kh = 0; kh < 3; ++kh)
#pragma unroll
    for (int kw = 0; kw < 3; ++kw) {
      const int sh = kh * 3 + kw;
      sh8 bf[3][2];
#pragma unroll
      for (int nt = 0; nt < 3; ++nt)
#pragma unroll
        for (int ks = 0; ks < 2; ++ks)
          bf[nt][ks] = *reinterpret_cast<const sh8*>(
              w2t + ((size_t)(sh * 48 + nt * 16 + ln15) * 64 + ks * 32 + q4 * 8));
#pragma unroll
      for (int i = 0; i < 4; ++i) {
        const int mt = w4 + i;
        const int lsr = (mt >> 1) + kh;      // local src row 0..9
        const int gsr = r0 + lsr - 1;        // global image row
        if ((unsigned)gsr < 32u) {           // wave-uniform
          const int w_ = (mt & 1) * 16 + ln15;
          const int cc = w_ + kw - 1;
          const bool cv = (unsigned)cc < 32u;
          int p = lsr * 32 + cc;
          p = p < 0 ? 0 : (p > 319 ? 319 : p);
#pragma unroll
          for (int ks = 0; ks < 2; ++ks) {
            sh8 af = *reinterpret_cast<const sh8*>(
                &xt[p * 64 + (((ks << 2) | q4) ^ (p & 7)) * 8]);
            af = cv ? af : zz;
            acc[i][0] = __builtin_amdgcn_mfma_f32_16x16x32_bf16(af, bf[0][ks], acc[i][0], 0, 0, 0);
            acc[i][1] = __builtin_amdgcn_mfma_f32_16x16x32_bf16(af, bf[1][ks], acc[i][1], 0, 0, 0);
            acc[i][2] = __builtin_amdgcn_mfma_f32_16x16x32_bf16(af, bf[2][ks], acc[i][2], 0, 0, 0);
          }
        }
      }
    }

  __syncthreads();  // done reading xt; reuse as pooled staging [48 oc][64 p]

  float bias[3];
#pragma unroll
  for (int nt = 0; nt < 3; ++nt) bias[nt] = b2s[nt * 16 + ln15];

  unsigned short* ps = reinterpret_cast<unsigned short*>(xt);
#pragma unroll
  for (int a = 0; a < 2; ++a) {
#pragma unroll
    for (int nt = 0; nt < 3; ++nt) {
      const f4 A = acc[a][nt], Bv = acc[a + 2][nt];
#pragma unroll
      for (int pr = 0; pr < 2; ++pr) {
        float m = fmaxf(fmaxf(A[pr * 2], A[pr * 2 + 1]),
                        fmaxf(Bv[pr * 2], Bv[pr * 2 + 1]));
        m = fmaxf(m + bias[nt], 0.f);
        const int pl = w * 16 + a * 8 + q4 * 2 + pr;  // 0..63 pooled idx in quarter
        ps[(nt * 16 + ln15) * 64 + pl] = f2bf(m);
      }
    }
  }
  __syncthreads();

  const int4* psv = reinterpret_cast<const int4*>(xt);
  int4* po = reinterpret_cast<int4*>(pooledt);
  for (int c = t; c < 384; c += 256) {
    const int j = c >> 3, sub = c & 7;
    po[(size_t)(j * 32 + quarter * 8 + sub) * 128 + b] = psv[c];
  }
}

// ---------------- K4: bf16 MFMA GEMM partials. BM=128, BN=32, K split 16 ----------
__global__ __launch_bounds__(256) void k4_fc(
    const unsigned short* __restrict__ pooledt, const float* __restrict__ fc_w,
    const int* __restrict__ sel, float* __restrict__ fcpart) {
  const int ntile = blockIdx.x;  // 0..31  (BN=32)
  const int ks = blockIdx.y;     // 0..15  (K chunk = 768 = 3 channels)
  const int t = threadIdx.x;
  const int w = t >> 6, l = t & 63;

  __shared__ short Ab[2][8192];  // [ko 8][m 128][8] bf16
  __shared__ short Bb[2][2048];  // [ko 8][n 32][8] bf16

  f4 acc[2][2];
  const f4 fzero = {0.f, 0.f, 0.f, 0.f};
#pragma unroll
  for (int i = 0; i < 2; ++i)
#pragma unroll
    for (int j = 0; j < 2; ++j) acc[i][j] = fzero;

  int ch[3];
#pragma unroll
  for (int i = 0; i < 3; ++i)
    ch[i] = __builtin_amdgcn_readfirstlane(sel[ks * 3 + i]);

  const int n0 = ntile * 32;
  const int nl = t & 31;
  int ng = n0 + nl; if (ng > 999) ng = 999;  // clamp tail rows (k5 ignores)
  const int kh = t >> 5;  // 0..7 k-oct
  const float* wrow = fc_w + (size_t)ng * 65536 + kh * 8;

  const int4* pt = reinterpret_cast<const int4*>(pooledt);
  const int kb0 = ks * 96;

  int4 av[4];
  float4 bv0, bv1;

  {  // stage tile 0
#pragma unroll
    for (int it = 0; it < 4; ++it) {
      const int s = it * 256 + t, ko = s >> 7, m = s & 127;
      av[it] = pt[(kb0 + ko) * 128 + m];
    }
    const float* bp = wrow + ch[0] * 256;
    bv0 = *reinterpret_cast<const float4*>(bp);
    bv1 = *reinterpret_cast<const float4*>(bp + 4);
#pragma unroll
    for (int it = 0; it < 4; ++it)
      *reinterpret_cast<int4*>(&Ab[0][(it * 256 + t) * 8]) = av[it];
    int4 bw;
    bw.x = f2bf(bv0.x) | ((unsigned)f2bf(bv0.y) << 16);
    bw.y = f2bf(bv0.z) | ((unsigned)f2bf(bv0.w) << 16);
    bw.z = f2bf(bv1.x) | ((unsigned)f2bf(bv1.y) << 16);
    bw.w = f2bf(bv1.z) | ((unsigned)f2bf(bv1.w) << 16);
    *reinterpret_cast<int4*>(&Bb[0][(kh * 32 + nl) * 8]) = bw;
  }
  __syncthreads();

  for (int tt = 0; tt < 12; ++tt) {
    const int cur = tt & 1, nxt = cur ^ 1;
    if (tt < 11) {
      const int tn = tt + 1;
#pragma unroll
      for (int it = 0; it < 4; ++it) {
        const int s = it * 256 + t, ko = s >> 7, m = s & 127;
        av[it] = pt[(kb0 + tn * 8 + ko) * 128 + m];
      }
      const float* bp = wrow + ch[tn >> 2] * 256 + (tn & 3) * 64;
      bv0 = *reinterpret_cast<const float4*>(bp);
      bv1 = *reinterpret_cast<const float4*>(bp + 4);
    }

#pragma unroll
    for (int s2 = 0; s2 < 2; ++s2) {
      const int kg = s2 * 4 + (l >> 4);
      const int m0 = w * 32 + (l & 15);
      sh8 a0 = *reinterpret_cast<const sh8*>(&Ab[cur][(kg * 128 + m0) * 8]);
      sh8 a1 = *reinterpret_cast<const sh8*>(&Ab[cur][(kg * 128 + m0 + 16) * 8]);
      sh8 b0 = *reinterpret_cast<const sh8*>(&Bb[cur][(kg * 32 + (l & 15)) * 8]);
      sh8 b1 = *reinterpret_cast<const sh8*>(&Bb[cur][(kg * 32 + 16 + (l & 15)) * 8]);
      acc[0][0] = __builtin_amdgcn_mfma_f32_16x16x32_bf16(a0, b0, acc[0][0], 0, 0, 0);
      acc[0][1] = __builtin_amdgcn_mfma_f32_16x16x32_bf16(a0, b1, acc[0][1], 0, 0, 0);
      acc[1][0] = __builtin_amdgcn_mfma_f32_16x16x32_bf16(a1, b0, acc[1][0], 0, 0, 0);
      acc[1][1] = __builtin_amdgcn_mfma_f32_16x16x32_bf16(a1, b1, acc[1][1], 0, 0, 0);
    }

    if (tt < 11) {
#pragma unroll
      for (int it = 0; it < 4; ++it)
        *reinterpret_cast<int4*>(&Ab[nxt][(it * 256 + t) * 8]) = av[it];
      int4 bw;
      bw.x = f2bf(bv0.x) | ((unsigned)f2bf(bv0.y) << 16);
      bw.y = f2bf(bv0.z) | ((unsigned)f2bf(bv0.w) << 16);
      bw.z = f2bf(bv1.x) | ((unsigned)f2bf(bv1.y) << 16);
      bw.w = f2bf(bv1.z) | ((unsigned)f2bf(bv1.w) << 16);
      *reinterpret_cast<int4*>(&Bb[nxt][(kh * 32 + nl) * 8]) = bw;
    }
    __syncthreads();
  }

  const int r0 = (l >> 4) * 4;
#pragma unroll
  for (int fm = 0; fm < 2; ++fm)
#pragma unroll
    for (int fn = 0; fn < 2; ++fn)
#pragma unroll
      for (int r = 0; r < 4; ++r) {
        const int m = w * 32 + fm * 16 + r0 + r;
        const int nc = n0 + fn * 16 + (l & 15);
        fcpart[(((size_t)ks * 128 + m) << 10) + nc] = acc[fm][fn][r];
      }
}

// ---------------- K5: reduce K-split partials + bias ------------------------------
__global__ __launch_bounds__(256) void k5_reduce(
    const float* __restrict__ fcpart, const float* __restrict__ fc_b,
    float* __restrict__ out) {
  const int id = blockIdx.x * 256 + threadIdx.x;  // 0..127999
  const int b = id / 1000;
  const int n = id - b * 1000;
  float s = fc_b[n];
#pragma unroll
  for (int ks = 0; ks < 16; ++ks)
    s += fcpart[(((size_t)ks * 128 + b) << 10) + n];
  out[id] = s;
}

extern "C" void kernel_launch(void* const* d_in, const int* in_sizes, int n_in,
                              void* d_out, int out_size, void* d_ws, size_t ws_size,
                              hipStream_t stream) {
  (void)in_sizes; (void)n_in; (void)out_size; (void)ws_size;
  const float* x0     = (const float*)d_in[0];
  const float* w1     = (const float*)d_in[1];
  const float* b1     = (const float*)d_in[2];
  const float* gate_w = (const float*)d_in[3];
  const float* w2     = (const float*)d_in[4];
  const float* b2     = (const float*)d_in[5];
  const float* fc_w   = (const float*)d_in[6];
  const float* fc_b   = (const float*)d_in[7];
  float* out = (float*)d_out;

  char* ws = (char*)d_ws;
  unsigned short* x1      = (unsigned short*)(ws);             // 16,777,216 B
  unsigned short* pooledt = (unsigned short*)(ws + 16777216);  //  3,145,728 B
  float*          part2   = (float*)(ws + 19922944);           //    131,072 B
  int*            sel     = (int*)  (ws + 20054016);           //        256 B
  unsigned short* w2t     = (unsigned short*)(ws + 20054272);  //     55,296 B
  float*          b2s     = (float*)(ws + 20109568);           //        768 B
  float*          fcpart  = (float*)(ws + 20110336);           //  8,388,608 B (ends ~28.5MB)

  hipLaunchKernelGGL(k1_conv1, dim3(128, 4), dim3(256), 0, stream, x0, w1, b1, x1, part2);
  hipLaunchKernelGGL(k2_select, dim3(1), dim3(256), 0, stream, part2, gate_w, sel);
  hipLaunchKernelGGL(k2b_wprep, dim3(48), dim3(256), 0, stream, w2, b2, sel, w2t, b2s);
  hipLaunchKernelGGL(k3_conv2, dim3(128, 4), dim3(256), 0, stream, x1, w2t, b2s, pooledt);
  hipLaunchKernelGGL(k4_fc, dim3(32, 16), dim3(256), 0, stream, pooledt, fc_w, sel, fcpart);
  hipLaunchKernelGGL(k5_reduce, dim3(500), dim3(256), 0, stream, fcpart, fc_b, out);
}